// Round 10
// baseline (202.931 us; speedup 1.0000x reference)
//
#include <hip/hip_runtime.h>
#include <hip/hip_bf16.h>

#define N_NODES 8192
#define N_IN 512
#define N_OUT 512

typedef __bf16 bf16;
typedef __bf16 bf16x4 __attribute__((ext_vector_type(4)));
typedef __bf16 bf16x8 __attribute__((ext_vector_type(8)));
typedef float f32x4 __attribute__((ext_vector_type(4)));

__device__ __forceinline__ void gload16(const void* g, void* l) {
  __builtin_amdgcn_global_load_lds((const __attribute__((address_space(1))) void*)g,
                                   (__attribute__((address_space(3))) void*)l, 16, 0, 0);
}

#define WAITVM(N) asm volatile("s_waitcnt vmcnt(" #N ")" ::: "memory")
#define BAR() do { asm volatile("" ::: "memory"); __builtin_amdgcn_s_barrier(); \
                   asm volatile("" ::: "memory"); } while (0)

// ---- kernel 1: column partial sums of adj (PURE READ - no bf16 copy anymore) ----
__global__ __launch_bounds__(256) void k_colsum(const float* __restrict__ adj,
                                                float* __restrict__ partial) {
  const int tid  = threadIdx.x;
  const int col0 = blockIdx.x * 1024 + tid * 4;
  const int row0 = blockIdx.y * 64;
  float s0 = 0.f, s1 = 0.f, s2 = 0.f, s3 = 0.f;
#pragma unroll 4
  for (int r = 0; r < 64; ++r) {
    const f32x4 v = *reinterpret_cast<const f32x4*>(adj + (size_t)(row0 + r) * N_NODES + col0);
    s0 += v[0]; s1 += v[1]; s2 += v[2]; s3 += v[3];
  }
  f32x4 ps = { s0, s1, s2, s3 };
  *reinterpret_cast<f32x4*>(partial + (size_t)blockIdx.y * N_NODES + col0) = ps;
}

// ---- kernel 2: d[j] = rsqrt(1 + colsum)  (+1 = self-loop) ----
__global__ __launch_bounds__(256) void k_dvec(const float* __restrict__ partial,
                                              float* __restrict__ dv) {
  const int j = blockIdx.x * 256 + threadIdx.x;
  float s = 1.0f;
#pragma unroll 8
  for (int p = 0; p < 128; ++p) s += partial[(size_t)p * N_NODES + j];
  dv[j] = rsqrtf(s);
}

// ---- kernel 3: Hst[k][j] = d[j]*H[j][k]  (transpose+scale, bf16; B^T for GEMM1) ----
__global__ __launch_bounds__(256) void k_hst(const float* __restrict__ H,
                                             const float* __restrict__ dv,
                                             bf16* __restrict__ Hst) {
  __shared__ float t[64][65];
  const int tid = threadIdx.x;
  const int j0 = blockIdx.x * 64;
  const int k0 = blockIdx.y * 64;
  const int rr = tid >> 4;
  const int cc = (tid & 15) * 4;
#pragma unroll
  for (int p = 0; p < 4; ++p) {
    const int r = p * 16 + rr;
    const float d = dv[j0 + r];
    f32x4 v = *reinterpret_cast<const f32x4*>(H + (size_t)(j0 + r) * N_IN + k0 + cc);
    t[r][cc + 0] = v[0] * d; t[r][cc + 1] = v[1] * d;
    t[r][cc + 2] = v[2] * d; t[r][cc + 3] = v[3] * d;
  }
  __syncthreads();
#pragma unroll
  for (int p = 0; p < 4; ++p) {
    const int kr = p * 16 + rr;
    bf16x4 o = { (bf16)t[cc + 0][kr], (bf16)t[cc + 1][kr],
                 (bf16)t[cc + 2][kr], (bf16)t[cc + 3][kr] };
    *reinterpret_cast<bf16x4*>(Hst + (size_t)(k0 + kr) * N_NODES + j0 + cc) = o;
  }
}

// ---- kernel 4: W fp32 -> bf16 ----
__global__ __launch_bounds__(256) void k_wcvt(const float* __restrict__ W, bf16* __restrict__ Wb) {
  const int i = (blockIdx.x * 256 + threadIdx.x) * 4;
  f32x4 v = *reinterpret_cast<const f32x4*>(W + i);
  bf16x4 o = { (bf16)v[0], (bf16)v[1], (bf16)v[2], (bf16)v[3] };
  *reinterpret_cast<bf16x4*>(Wb + i) = o;
}

// ========== gemm1: 256x256 tile, A = RAW FP32 adj (reg-staged + cvt), ==========
// B = bf16 Hst via global_load_lds. Double-buffered 2x64KB LDS, 8 waves
// (2Mx4N, wave 128x64), split-K=4 -> 256 blocks (1/CU).
// Per K-tile: {issue A-regs(t+1) + B-gloads(t+1)} -> 64 MFMA on t (~2000cyc,
// covers HBM latency; depth-1 suffices) -> cvt+swizzled ds_write(t+1) ->
// __syncthreads (compiler-managed full waitcnt drain). adjb buffer ELIMINATED:
// A comes straight from adj (L3-warm after colsum). +I handled in k_red.
template<int KDIM, int NSPLIT>
__global__ __launch_bounds__(512, 1) void k_gemm1(
    const float* __restrict__ A, const bf16* __restrict__ B, bf16* __restrict__ P) {
  constexpr int KSEG = KDIM / NSPLIT;          // 2048
  constexpr int NT = KSEG / 64;                // 32 K-tiles
  constexpr int NBLK = 64 * NSPLIT;            // 256
  __shared__ __attribute__((aligned(128))) char lds[2 * 65536];

  // XCD swizzle (bijective); N-minor so both N-halves of an A-panel co-run.
  const int bid = blockIdx.x;
  const int l = (bid & 7) * (NBLK / 8) + (bid >> 3);
  const int split = l / 64;
  const int rem = l % 64;
  const int bm0 = (rem >> 1) * 256;
  const int bn0 = (rem & 1) * 256;

  const int tid = threadIdx.x;
  const int lane = tid & 63;
  const int wid = tid >> 6;
  const int wr = wid >> 2;                     // 0..1 (M half)
  const int wc = wid & 3;                      // 0..3 (N quarter)
  const size_t koff = (size_t)split * KSEG;

  // A staging: thread -> row tid>>1 (0..255), half-row (tid&1)*32 fp32.
  const int arow = tid >> 1;
  const int acol = (tid & 1) * 32;
  const float* aG = A + (size_t)(bm0 + arow) * KDIM + koff + acol;
  const int arowb = arow * 128;                // LDS byte base of row
  const int ar7 = arow & 7;

  // B staging: linear LDS dest, inverse-swizzled global source.
  const int srow = tid >> 3;                   // 0..63
  const int sslot = (tid & 7) ^ (srow & 7);
  const bf16* bG = B + (size_t)(bn0 + srow) * KDIM + koff + sslot * 8;
  const int wuni = wid * 1024;

  // fragment reads: logical slot = kk*4+fk, phys = logical ^ (row&7)
  const int frow = lane & 15;
  const int fk = lane >> 4;
  const int e7 = lane & 7;
  const int sb0 = ((fk) ^ e7) << 4;
  const int sb1 = ((4 + fk) ^ e7) << 4;
  const int aBase = wr * 16384 + frow * 128;                 // + m*2048
  const int bBase = 32768 + (wc * 64 + frow) * 128;          // + n*2048

  f32x4 acc[8][4] = {};
  f32x4 fr[8];                                 // A in-flight registers (32 fp32)

  auto A_issue = [&](int t) {
    const float* g = aG + (size_t)t * 64;
#pragma unroll
    for (int q = 0; q < 8; ++q)
      fr[q] = *reinterpret_cast<const f32x4*>(g + q * 4);
  };
  auto A_write = [&](int buf) {                // cvt + swizzled ds_write_b128 x4
    char* lb = lds + buf * 65536;
#pragma unroll
    for (int s = 0; s < 4; ++s) {
      bf16x8 o;
#pragma unroll
      for (int e = 0; e < 4; ++e) { o[e] = (bf16)fr[2 * s][e]; o[e + 4] = (bf16)fr[2 * s + 1][e]; }
      const int slot = ((tid & 1) * 4 + s) ^ ar7;
      *reinterpret_cast<bf16x8*>(lb + arowb + slot * 16) = o;
    }
  };
  auto GB = [&](int t, int buf) {              // 4 x global_load_lds (256 B-rows)
    const bf16* g = bG + (size_t)t * 64;
    char* d = lds + buf * 65536 + 32768 + wuni;
#pragma unroll
    for (int c = 0; c < 4; ++c)
      gload16(g + (size_t)(c * 64) * KDIM, d + c * 8192);
  };
  auto compute = [&](int buf) {
    const char* lb = lds + buf * 65536;
#pragma unroll
    for (int kk = 0; kk < 2; ++kk) {
      const int sb = kk ? sb1 : sb0;
      bf16x8 bv[4];
#pragma unroll
      for (int n = 0; n < 4; ++n)
        bv[n] = *reinterpret_cast<const bf16x8*>(lb + bBase + n * 2048 + sb);
#pragma unroll
      for (int m = 0; m < 8; ++m) {
        const bf16x8 a = *reinterpret_cast<const bf16x8*>(lb + aBase + m * 2048 + sb);
#pragma unroll
        for (int n = 0; n < 4; ++n)
          acc[m][n] = __builtin_amdgcn_mfma_f32_16x16x32_bf16(a, bv[n], acc[m][n], 0, 0, 0);
      }
    }
  };

  // prologue: tile 0 into buf 0
  A_issue(0); GB(0, 0); A_write(0);
  __syncthreads();

#pragma unroll 1
  for (int t = 0; t < NT; ++t) {
    const bool pf = (t + 1 < NT);
    if (pf) { A_issue(t + 1); GB(t + 1, (t + 1) & 1); }   // fly during compute
    compute(t & 1);
    if (pf) A_write((t + 1) & 1);            // vmcnt wait auto-inserted before cvt
    __syncthreads();                         // drains gload_lds + ds_writes
  }

  // epilogue: C/D layout col = lane&15, row = (lane>>4)*4 + j ; bf16 partials
#pragma unroll
  for (int m = 0; m < 8; ++m) {
#pragma unroll
    for (int j = 0; j < 4; ++j) {
      const int grow = bm0 + wr * 128 + m * 16 + (lane >> 4) * 4 + j;
      bf16* prow = P + (size_t)split * ((size_t)N_NODES * N_IN) + (size_t)grow * N_IN;
#pragma unroll
      for (int n = 0; n < 4; ++n) {
        const int gcol = bn0 + wc * 64 + n * 16 + (lane & 15);
        prow[gcol] = (bf16)acc[m][n][j];
      }
    }
  }
}

// ---- 128x128-tile GEMM (gemm2): out = tanh(A @ B^T + bias), verified structure ----
template<int KDIM>
__global__ __launch_bounds__(256, 2) void k_gemm(
    const bf16* __restrict__ A, const bf16* __restrict__ B,
    const float* __restrict__ bias, float* __restrict__ outf) {
  constexpr int NT = KDIM / 64;
  constexpr int NBLK = 256;
  __shared__ __attribute__((aligned(128))) char lds[2 * 32768];

  const int bid = blockIdx.x;
  const int logical = (bid & 7) * (NBLK / 8) + (bid >> 3);
  const int bm0 = (logical >> 2) * 128;
  const int bn0 = (logical & 3) * 128;

  const int tid = threadIdx.x;
  const int wid = tid >> 6;
  const int lane = tid & 63;
  const int wr = wid & 1, wc = wid >> 1;

  const int srow = tid >> 3;
  const int scol = ((tid & 7) ^ (srow & 7)) << 3;
  const size_t a_src = (size_t)(bm0 + srow) * KDIM + scol;
  const size_t b_src = (size_t)(bn0 + srow) * KDIM + scol;

  const int frow = lane & 15;
  const int fk = lane >> 4;
  const int swz = (lane & 7) << 4;
  const int a_row_byte = (wr * 64 + frow) * 128;
  const int b_row_byte = 16384 + (wc * 64 + frow) * 128;

  f32x4 acc[4][4] = {};

  auto stage = [&](int t) {
    char* lbase = lds + (t & 1) * 32768;
    const bf16* ag = A + a_src + (size_t)t * 64;
    const bf16* bg = B + b_src + (size_t)t * 64;
#pragma unroll
    for (int ch = 0; ch < 4; ++ch) {
      gload16(ag + (size_t)(ch * 32) * KDIM, lbase + ch * 4096 + wid * 1024);
      gload16(bg + (size_t)(ch * 32) * KDIM, lbase + 16384 + ch * 4096 + wid * 1024);
    }
  };

  auto compute = [&](int t) {
    const char* lbase = lds + (t & 1) * 32768;
#pragma unroll
    for (int kk = 0; kk < 2; ++kk) {
      const int colb = (kk * 64 + fk * 16) ^ swz;
      bf16x8 av[4], bv[4];
#pragma unroll
      for (int m = 0; m < 4; ++m)
        av[m] = *reinterpret_cast<const bf16x8*>(lbase + a_row_byte + m * 2048 + colb);
#pragma unroll
      for (int n = 0; n < 4; ++n)
        bv[n] = *reinterpret_cast<const bf16x8*>(lbase + b_row_byte + n * 2048 + colb);
#pragma unroll
      for (int m = 0; m < 4; ++m)
#pragma unroll
        for (int n = 0; n < 4; ++n)
          acc[m][n] = __builtin_amdgcn_mfma_f32_16x16x32_bf16(av[m], bv[n], acc[m][n], 0, 0, 0);
    }
  };

  stage(0);
#pragma unroll 1
  for (int t = 0; t < NT - 1; ++t) {
    stage(t + 1);
    WAITVM(8);
    BAR();
    compute(t);
    BAR();
  }
  WAITVM(0);
  BAR();
  compute(NT - 1);

#pragma unroll
  for (int m = 0; m < 4; ++m) {
#pragma unroll
    for (int j = 0; j < 4; ++j) {
      const int grow = bm0 + wr * 64 + m * 16 + (lane >> 4) * 4 + j;
      float* orow = outf + (size_t)grow * N_OUT;
#pragma unroll
      for (int n = 0; n < 4; ++n) {
        const int gcol = bn0 + wc * 64 + n * 16 + (lane & 15);
        float v = acc[m][n][j] + bias[gcol];
        v = fminf(fmaxf(v, -15.f), 15.f);
        const float e = __expf(2.f * v);
        orow[gcol] = (e - 1.f) / (e + 1.f);
      }
    }
  }
}

// ---- split-K reduce + GCN epilogue: Hm = bf16(d_i*(P0+..+P3) + d_i^2*H) ----
__global__ __launch_bounds__(256) void k_red(const bf16* __restrict__ P,
                                             const float* __restrict__ H,
                                             const float* __restrict__ dv,
                                             bf16* __restrict__ Hm) {
  const int t = blockIdx.x * 256 + threadIdx.x;
  const int row = t >> 6;
  const int col = (t & 63) << 3;
  const size_t off = (size_t)row * N_IN + col;
  constexpr size_t S = (size_t)N_NODES * N_IN;
  const float d = dv[row];
  const float d2 = d * d;
  const bf16x8 p0 = *reinterpret_cast<const bf16x8*>(P + off);
  const bf16x8 p1 = *reinterpret_cast<const bf16x8*>(P + S + off);
  const bf16x8 p2 = *reinterpret_cast<const bf16x8*>(P + 2 * S + off);
  const bf16x8 p3 = *reinterpret_cast<const bf16x8*>(P + 3 * S + off);
  const f32x4 h0 = *reinterpret_cast<const f32x4*>(H + off);
  const f32x4 h1 = *reinterpret_cast<const f32x4*>(H + off + 4);
  bf16x8 o;
#pragma unroll
  for (int e = 0; e < 8; ++e) {
    const float h = (e < 4) ? h0[e & 3] : h1[e & 3];
    o[e] = (bf16)(d * (((float)p0[e] + (float)p1[e]) + ((float)p2[e] + (float)p3[e])) + d2 * h);
  }
  *reinterpret_cast<bf16x8*>(Hm + off) = o;
}

extern "C" void kernel_launch(void* const* d_in, const int* in_sizes, int n_in,
                              void* d_out, int out_size, void* d_ws, size_t ws_size,
                              hipStream_t stream) {
  const float* H   = (const float*)d_in[0];
  const float* adj = (const float*)d_in[1];
  const float* W   = (const float*)d_in[2];
  const float* b   = (const float*)d_in[3];
  float* out = (float*)d_out;
  char* ws = (char*)d_ws;

  bf16*  Hst  = (bf16*)(ws);                    // 512*8192*2  = 8388608
  bf16*  Hm   = (bf16*)(ws + 8388608);          // 8192*512*2  = 8388608
  bf16*  Wb   = (bf16*)(ws + 16777216);         // 512*512*2   = 524288
  float* part = (float*)(ws + 17301504);        // 128*8192*4  = 4194304
  float* dv   = (float*)(ws + 21495808);        // 8192*4      = 32768
  bf16*  P    = (bf16*)(ws + 21528576);         // 4*8192*512*2 = 33554432

  k_colsum<<<dim3(8, 128), 256, 0, stream>>>(adj, part);
  k_dvec<<<32, 256, 0, stream>>>(part, dv);
  k_hst<<<dim3(128, 8), 256, 0, stream>>>(H, dv, Hst);
  k_wcvt<<<256, 256, 0, stream>>>(W, Wb);
  // P[s] = adj[:, s-quarter] @ Hst[s-quarter]^T   (raw fp32 A, split-K=4, bf16 P)
  k_gemm1<8192, 4><<<256, 512, 0, stream>>>(adj, Hst, P);
  // Hm = d_i*(P0+P1+P2+P3) + d_i^2*H   (+I term here; adjb eliminated)
  k_red<<<2048, 256, 0, stream>>>(P, H, dv, Hm);
  // out = tanh(Hm @ W^T + b)  (f32)
  k_gemm<512><<<256, 256, 0, stream>>>(Hm, Wb, b, out);
}